// Round 5
// baseline (322.101 us; speedup 1.0000x reference)
//
#include <hip/hip_runtime.h>
#include <cmath>

typedef __bf16 bf16_t;
typedef bf16_t bf16x8 __attribute__((ext_vector_type(8)));
typedef bf16_t bf16x4 __attribute__((ext_vector_type(4)));
typedef float  f32x4  __attribute__((ext_vector_type(4)));

#define Bn  4
#define TQn 1024
#define TKn 1024
#define En  1024
#define Hn  16
#define DHn 64

static constexpr float EPSv = 1e-5f;
// softmax in exp2 domain: scale = (1/sqrt(64)) * log2(e)
static constexpr float C_SCALE = 0.18033688011112042f;

#define GLDS16(g, l)                                                         \
    __builtin_amdgcn_global_load_lds(                                        \
        (const __attribute__((address_space(1))) void*)(g),                  \
        (__attribute__((address_space(3))) void*)(l), 16, 0, 0)

// ---------------------------------------------------------------------------
// fp32 -> bf16 conversion, all tensors fused; also zeroes the GN stats accum.
// ---------------------------------------------------------------------------
__global__ __launch_bounds__(256)
void cvt_all(const float* __restrict__ x, const float* __restrict__ enc,
             const float* __restrict__ q1w, const float* __restrict__ q2w,
             const float* __restrict__ k1w, const float* __restrict__ k2w,
             const float* __restrict__ vw,  const float* __restrict__ outw,
             bf16_t* __restrict__ xb, bf16_t* __restrict__ encb,
             bf16_t* __restrict__ wq, bf16_t* __restrict__ wkv,
             bf16_t* __restrict__ wob, float* __restrict__ stats)
{
    if (blockIdx.x == 0 && threadIdx.x < 128) stats[threadIdx.x] = 0.f;
    int idx = blockIdx.x * 256 + threadIdx.x;   // 0 .. 3670015
    const float* src; bf16_t* dst;
    if      (idx < 1048576) { src = x    + (size_t)idx * 4;              dst = xb   + (size_t)idx * 4; }
    else if (idx < 2097152) { src = enc  + (size_t)(idx - 1048576) * 4;  dst = encb + (size_t)(idx - 1048576) * 4; }
    else if (idx < 2359296) { src = q1w  + (size_t)(idx - 2097152) * 4;  dst = wq   + (size_t)(idx - 2097152) * 4; }
    else if (idx < 2621440) { src = q2w  + (size_t)(idx - 2359296) * 4;  dst = wq   + 1048576 + (size_t)(idx - 2359296) * 4; }
    else if (idx < 2883584) { src = k1w  + (size_t)(idx - 2621440) * 4;  dst = wkv  + (size_t)(idx - 2621440) * 4; }
    else if (idx < 3145728) { src = k2w  + (size_t)(idx - 2883584) * 4;  dst = wkv  + 1048576 + (size_t)(idx - 2883584) * 4; }
    else if (idx < 3407872) { src = vw   + (size_t)(idx - 3145728) * 4;  dst = wkv  + 2097152 + (size_t)(idx - 3145728) * 4; }
    else                    { src = outw + (size_t)(idx - 3407872) * 4;  dst = wob  + (size_t)(idx - 3407872) * 4; }
    float4 v = *(const float4*)src;
    bf16x4 o;
    o[0] = (bf16_t)v.x; o[1] = (bf16_t)v.y; o[2] = (bf16_t)v.z; o[3] = (bf16_t)v.w;
    *(bf16x4*)dst = o;
}

// ---------------------------------------------------------------------------
// MFMA GEMM (m97 recipe): 128x128 tile, BK=64, GLDS16 staging w/ source
// swizzle, XOR-swizzled LDS, 4 waves 2x2, mfma_f32_16x16x32_bf16.
// C[m,n] = sum_k A[m,k] * W[n,k] + bias(n)
// OUTMODE 0: scatter bf16 to [seg,b,h,t,d]
// OUTMODE 2: same, but seg 2 (V) stored transposed [seg,b,h,d,t]
// OUTMODE 1: fp32 row-major [M,1024]
// ---------------------------------------------------------------------------
template<int OUTMODE>
__global__ __launch_bounds__(256, 3)
void gemm_bf16(const bf16_t* __restrict__ A, const bf16_t* __restrict__ W,
               const float* __restrict__ b0, const float* __restrict__ b1,
               const float* __restrict__ b2, void* __restrict__ Cout, int K)
{
    __shared__ bf16_t sA[128 * 64];
    __shared__ bf16_t sB[128 * 64];
    const int tid = threadIdx.x;
    const int w = tid >> 6, lane = tid & 63;
    const int q = lane >> 4, r = lane & 15;
    const int wm = w & 1, wn = w >> 1;
    const int blockM = blockIdx.y * 128, blockN = blockIdx.x * 128;

    f32x4 acc[4][4];
#pragma unroll
    for (int i = 0; i < 4; ++i)
#pragma unroll
        for (int j = 0; j < 4; ++j) acc[i][j] = (f32x4){0.f, 0.f, 0.f, 0.f};

    for (int k0 = 0; k0 < K; k0 += 64) {
#pragma unroll
        for (int c = 0; c < 4; ++c) {
            const int s = c * 256 + tid;
            const int row = s >> 3;
            const int cg = (s & 7) ^ (row & 7);     // source-swizzle for GLDS
            GLDS16(A + (size_t)(blockM + row) * K + k0 + cg * 8, sA + c * 2048 + w * 512);
            GLDS16(W + (size_t)(blockN + row) * K + k0 + cg * 8, sB + c * 2048 + w * 512);
        }
        __syncthreads();
#pragma unroll
        for (int ks = 0; ks < 2; ++ks) {
            bf16x8 a[4], b[4];
#pragma unroll
            for (int i = 0; i < 4; ++i) {
                const int row = wm * 64 + i * 16 + r;
                const int g = (ks * 4 + q) ^ (row & 7);
                a[i] = *(const bf16x8*)&sA[row * 64 + g * 8];
            }
#pragma unroll
            for (int j = 0; j < 4; ++j) {
                const int row = wn * 64 + j * 16 + r;
                const int g = (ks * 4 + q) ^ (row & 7);
                b[j] = *(const bf16x8*)&sB[row * 64 + g * 8];
            }
#pragma unroll
            for (int i = 0; i < 4; ++i)
#pragma unroll
                for (int j = 0; j < 4; ++j)
                    acc[i][j] = __builtin_amdgcn_mfma_f32_16x16x32_bf16(a[i], b[j], acc[i][j], 0, 0, 0);
        }
        __syncthreads();
    }

    const int seg = blockN >> 10;
    const float* bp = (seg == 0) ? b0 : ((seg == 1) ? b1 : b2);
#pragma unroll
    for (int j = 0; j < 4; ++j) {
        const int n = blockN + wn * 64 + j * 16 + r;
        const float bv = bp[n & 1023];
#pragma unroll
        for (int i = 0; i < 4; ++i) {
            f32x4 v = acc[i][j];
#pragma unroll
            for (int e = 0; e < 4; ++e) {
                const int m = blockM + wm * 64 + i * 16 + q * 4 + e;
                const float val = v[e] + bv;
                if (OUTMODE == 0 || OUTMODE == 2) {
                    const int bb = m >> 10, t = m & 1023;
                    const int h = (n >> 6) & 15, d = n & 63;
                    const size_t base = ((size_t)(seg * 4 + bb) * 16 + h) * 65536;
                    if (OUTMODE == 2 && seg == 2)
                        ((bf16_t*)Cout)[base + (size_t)d * 1024 + t] = (bf16_t)val;
                    else
                        ((bf16_t*)Cout)[base + (size_t)t * 64 + d] = (bf16_t)val;
                } else {
                    ((float*)Cout)[(size_t)m * 1024 + n] = val;
                }
            }
        }
    }
}

// ---------------------------------------------------------------------------
// Differential flash attention, bf16 MFMA, transposed-S, s-split wave groups.
// Grid dim3(64, 8): x = bh (XCD-local K/V), y = qt. Block 512 thr = 8 waves:
// waves 0-3 (group 0) process even 32-wide s-tiles, waves 4-7 (group 1) odd.
// Each wave owns 32 Q-rows (t). Partial (O, l) merged via LDS at the end
// (exp2-domain softmax without running max -> partials add exactly).
// LDS 40 KB -> 2 blocks/CU = 16 waves/CU = 4 waves/SIMD.
// V is pre-transposed [d][t] in global (by the KV GEMM) -> staged via GLDS.
// ---------------------------------------------------------------------------
__global__ __launch_bounds__(512, 4)
void diff_attn_mfma(const bf16_t* __restrict__ q12, const bf16_t* __restrict__ k12v,
                    const float* __restrict__ lam, bf16_t* __restrict__ out,
                    float* __restrict__ stats)
{
    // layout (bf16 elems): sK1[2][2048] | sK2[2][2048] | sVt[2][2048] | sPt[8][1024]
    __shared__ __align__(16) bf16_t smem[20480];   // 40,960 B

    const int tid = threadIdx.x;
    const int w = tid >> 6, lane = tid & 63;
    const int wg = w >> 2, wl = w & 3;          // s-group, wave-in-group
    const int q = lane >> 4, r = lane & 15;
    const int bh = blockIdx.x, qt = blockIdx.y;
    const float lamv = lam[bh & (Hn - 1)];

    bf16_t* sK1 = smem + wg * 2048;
    bf16_t* sK2 = smem + 4096 + wg * 2048;
    bf16_t* sVt = smem + 8192 + wg * 2048;
    bf16_t* sPt = smem + 12288 + w * 1024;      // wave-private [32 t][32 s]

    const size_t HT = (size_t)TKn * DHn;        // 65536
    const bf16_t* q1g = q12 + (size_t)bh * HT + ((size_t)qt * 128 + wl * 32) * 64;
    const bf16_t* q2g = q1g + 64 * HT;
    const bf16_t* k1g = k12v + (size_t)bh * HT;
    const bf16_t* k2g = k1g + 64 * HT;
    const bf16_t* vg  = k1g + 128 * HT;         // V^T: [d][t], row stride 1024

    // Q fragments in registers (B-operand layout), rows wl*32 .. +31
    bf16x8 fQ1[2][2], fQ2[2][2];
#pragma unroll
    for (int j = 0; j < 2; ++j) {
        const int t_l = j * 16 + r;
#pragma unroll
        for (int ks = 0; ks < 2; ++ks) {
            fQ1[j][ks] = *(const bf16x8*)(q1g + (size_t)t_l * 64 + ks * 32 + q * 8);
            fQ2[j][ks] = *(const bf16x8*)(q2g + (size_t)t_l * 64 + ks * 32 + q * 8);
        }
    }

    f32x4 O1[2][4], O2[2][4];
    float l1[2] = {0.f, 0.f}, l2[2] = {0.f, 0.f};
#pragma unroll
    for (int i = 0; i < 2; ++i)
#pragma unroll
        for (int j = 0; j < 4; ++j) { O1[i][j] = (f32x4){0.f,0.f,0.f,0.f}; O2[i][j] = (f32x4){0.f,0.f,0.f,0.f}; }

    const int tg = wl * 64 + lane;              // 0..255 within group
    // K staging indices: tile = 32 rows x 64 cols = 256 chunks of 16B
    const int krow = tg >> 3;
    const int kcg  = (tg & 7) ^ (krow & 7);
    // V^T staging: tile = 64 rows(d) x 32 cols(s) = 256 chunks
    const int vd  = tg >> 2;
    const int vcg = (tg & 3) ^ (vd & 3) ^ ((vd >> 2) & 3);
    const int swzr = (r & 3) ^ ((r >> 2) & 3);  // sPt/fV row swizzle for row=..+r

    for (int st = wg; st < 32; st += 2) {
        __syncthreads();   // prior tile's compute done; buffers free
        GLDS16(k1g + (size_t)st * 2048 + krow * 64 + kcg * 8, sK1 + wl * 512);
        GLDS16(k2g + (size_t)st * 2048 + krow * 64 + kcg * 8, sK2 + wl * 512);
        GLDS16(vg + (size_t)vd * 1024 + st * 32 + vcg * 8,    sVt + wl * 512);
        __syncthreads();   // data visible (barrier drains vmcnt)

        // V^T fragments (B-operand): d = j*16+r, k = s = q*8..+7
        bf16x8 fV[4];
#pragma unroll
        for (int j = 0; j < 4; ++j) {
            const int g = q ^ swzr;             // (d&3)^((d>>2)&3) == swzr
            fV[j] = *(const bf16x8*)&sVt[(j * 16 + r) * 32 + g * 8];
        }

        // ---- two streams: S^T = K·Q^T, exp2, P->LDS, O += P·V^T ----
#pragma unroll
        for (int stream = 0; stream < 2; ++stream) {
            const bf16_t* sK = stream ? sK2 : sK1;
            const bf16x8 (&fQ)[2][2] = stream ? fQ2 : fQ1;
            float* lp = stream ? l2 : l1;
            f32x4 (&O)[2][4] = stream ? O2 : O1;

            f32x4 S[2][2];
#pragma unroll
            for (int i = 0; i < 2; ++i)
#pragma unroll
                for (int j = 0; j < 2; ++j) S[i][j] = (f32x4){0.f,0.f,0.f,0.f};
#pragma unroll
            for (int ks = 0; ks < 2; ++ks) {
                bf16x8 fK[2];
#pragma unroll
                for (int i = 0; i < 2; ++i) {
                    const int g = (ks * 4 + q) ^ (r & 7);
                    fK[i] = *(const bf16x8*)&sK[(i * 16 + r) * 64 + g * 8];
                }
#pragma unroll
                for (int i = 0; i < 2; ++i)
#pragma unroll
                    for (int j = 0; j < 2; ++j)
                        S[i][j] = __builtin_amdgcn_mfma_f32_16x16x32_bf16(fK[i], fQ[j][ks], S[i][j], 0, 0, 0);
            }
            // exp2 + pack to sPt [t][s] (wave-private strip), accumulate l
#pragma unroll
            for (int j = 0; j < 2; ++j) {
                const int t_l = j * 16 + r;
                float part = 0.f;
#pragma unroll
                for (int i = 0; i < 2; ++i) {
                    bf16x4 pk;
#pragma unroll
                    for (int e = 0; e < 4; ++e) {
                        const float p = __builtin_amdgcn_exp2f(S[i][j][e] * C_SCALE);
                        part += p;
                        pk[e] = (bf16_t)p;
                    }
                    const int sg = i * 2 + (q >> 1);          // s-group 0..3
                    const int g = sg ^ swzr;                  // swz of t_l == swzr
                    *(bf16x4*)&sPt[t_l * 32 + g * 8 + (q & 1) * 4] = pk;
                }
                lp[j] += part;
            }
            // O += P·V^T  (single k=32 MFMA step)
            bf16x8 fP[2];
#pragma unroll
            for (int i2 = 0; i2 < 2; ++i2) {
                const int g = q ^ swzr;
                fP[i2] = *(const bf16x8*)&sPt[(i2 * 16 + r) * 32 + g * 8];
            }
#pragma unroll
            for (int i2 = 0; i2 < 2; ++i2)
#pragma unroll
                for (int j = 0; j < 4; ++j)
                    O[i2][j] = __builtin_amdgcn_mfma_f32_16x16x32_bf16(fP[i2], fV[j], O[i2][j], 0, 0, 0);
        }
    }

    // ---- merge group 1's partials into group 0 via LDS (two rounds) ----
    float* scr = (float*)smem;                  // 10240 floats available
    const int li = wl * 64 + lane;              // 0..255
    __syncthreads();
    if (wg == 1) {
#pragma unroll
        for (int i2 = 0; i2 < 2; ++i2)
#pragma unroll
            for (int j = 0; j < 4; ++j)
                *(f32x4*)&scr[li * 32 + (i2 * 4 + j) * 4] = O1[i2][j];
        f32x4 lv = {l1[0], l1[1], l2[0], l2[1]};
        *(f32x4*)&scr[8192 + li * 4] = lv;
    }
    __syncthreads();
    if (wg == 0) {
#pragma unroll
        for (int i2 = 0; i2 < 2; ++i2)
#pragma unroll
            for (int j = 0; j < 4; ++j)
                O1[i2][j] += *(const f32x4*)&scr[li * 32 + (i2 * 4 + j) * 4];
        f32x4 lv = *(const f32x4*)&scr[8192 + li * 4];
        l1[0] += lv[0]; l1[1] += lv[1]; l2[0] += lv[2]; l2[1] += lv[3];
    }
    __syncthreads();
    if (wg == 1) {
#pragma unroll
        for (int i2 = 0; i2 < 2; ++i2)
#pragma unroll
            for (int j = 0; j < 4; ++j)
                *(f32x4*)&scr[li * 32 + (i2 * 4 + j) * 4] = O2[i2][j];
    }
    __syncthreads();
    if (wg == 0) {
#pragma unroll
        for (int i2 = 0; i2 < 2; ++i2)
#pragma unroll
            for (int j = 0; j < 4; ++j)
                O2[i2][j] += *(const f32x4*)&scr[li * 32 + (i2 * 4 + j) * 4];

        // l reduction across q-groups (all lanes get row-sum for their r)
#pragma unroll
        for (int j = 0; j < 2; ++j) {
            l1[j] += __shfl_xor(l1[j], 16); l1[j] += __shfl_xor(l1[j], 32);
            l2[j] += __shfl_xor(l2[j], 16); l2[j] += __shfl_xor(l2[j], 32);
        }

        // epilogue: out (bf16 [bh][t][d]) + GN partial sums
        bf16_t* op = out + ((size_t)bh * TQn + (size_t)qt * 128 + wl * 32) * DHn;
        float ssum = 0.f, ssq = 0.f;
#pragma unroll
        for (int i2 = 0; i2 < 2; ++i2)
#pragma unroll
            for (int e = 0; e < 4; ++e) {
                const int rr = q * 4 + e;
                const float inv1 = 1.0f / __shfl(l1[i2], rr);
                const float inv2 = lamv / __shfl(l2[i2], rr);
                const int t_l = i2 * 16 + rr;
#pragma unroll
                for (int j = 0; j < 4; ++j) {
                    const float o = O1[i2][j][e] * inv1 - O2[i2][j][e] * inv2;
                    op[(size_t)t_l * 64 + j * 16 + r] = (bf16_t)o;
                    ssum += o;
                    ssq += o * o;
                }
            }
#pragma unroll
        for (int d = 1; d < 64; d <<= 1) {
            ssum += __shfl_xor(ssum, d);
            ssq  += __shfl_xor(ssq, d);
        }
        if (lane == 0) {
            atomicAdd(&stats[bh], ssum);
            atomicAdd(&stats[64 + bh], ssq);
        }
    }
}

// ---------------------------------------------------------------------------
// GroupNorm apply (mu/rstd from atomic sums) + transpose -> y bf16 [B*T,H*DH]
// ---------------------------------------------------------------------------
__global__ __launch_bounds__(256)
void gn_apply(const bf16_t* __restrict__ attn, const float* __restrict__ stats,
              const float* __restrict__ gamma, const float* __restrict__ beta,
              bf16_t* __restrict__ y)
{
    const int f = blockIdx.x * 256 + threadIdx.x;   // 8-elem group, 0..524287
    const int d8 = (f & 7) << 3;
    const int t  = (f >> 3) & 1023;
    const int bh = f >> 13;
    const int h  = bh & 15;
    const int b  = bh >> 4;
    const float s1 = stats[bh], s2 = stats[64 + bh];
    const float mu = s1 * (1.f / 65536.f);
    const float var = s2 * (1.f / 65536.f) - mu * mu;
    const float rstd = rsqrtf(var + EPSv);
    bf16x8 v = *(const bf16x8*)&attn[((size_t)bh << 16) + t * 64 + d8];
    const int c = h * 64 + d8;
    const float* gp = gamma + c;
    const float* bp = beta + c;
    bf16x8 o;
#pragma unroll
    for (int i = 0; i < 8; ++i)
        o[i] = (bf16_t)(((float)v[i] - mu) * rstd * gp[i] + bp[i]);
    *(bf16x8*)&y[((size_t)(b * 1024 + t)) * 1024 + c] = o;
}

// ---------------------------------------------------------------------------
extern "C" void kernel_launch(void* const* d_in, const int* in_sizes, int n_in,
                              void* d_out, int out_size, void* d_ws, size_t ws_size,
                              hipStream_t stream)
{
    const float* x    = (const float*)d_in[0];
    const float* enc  = (const float*)d_in[1];
    const float* Q1w  = (const float*)d_in[2];
    const float* Q1b  = (const float*)d_in[3];
    const float* Q2w  = (const float*)d_in[4];
    const float* Q2b  = (const float*)d_in[5];
    const float* K1w  = (const float*)d_in[6];
    const float* K1b  = (const float*)d_in[7];
    const float* K2w  = (const float*)d_in[8];
    const float* K2b  = (const float*)d_in[9];
    const float* Vw   = (const float*)d_in[10];
    const float* Vb   = (const float*)d_in[11];
    const float* lam  = (const float*)d_in[12];
    const float* gng  = (const float*)d_in[13];
    const float* gnb  = (const float*)d_in[14];
    const float* outw = (const float*)d_in[15];
    const float* outb = (const float*)d_in[16];
    float* out = (float*)d_out;

    // workspace layout (bf16 elems unless noted)
    bf16_t* xb   = (bf16_t*)d_ws;            // 4,194,304
    bf16_t* encb = xb   + 4194304;           // 4,194,304
    bf16_t* wq   = encb + 4194304;           // 2,097,152  [Q1w|Q2w]
    bf16_t* wkv  = wq   + 2097152;           // 3,145,728  [K1w|K2w|Vw]
    bf16_t* wob  = wkv  + 3145728;           // 1,048,576
    bf16_t* q12  = wob  + 1048576;           // 8,388,608  [2][B][H][T][D]
    bf16_t* k12v = q12  + 8388608;           // 12,582,912 [K1|K2: t,d][V: d,t]
    bf16_t* yb   = k12v + 12582912;          // 4,194,304
    bf16_t* attnb= yb   + 4194304;           // 4,194,304
    float*  stats= (float*)(attnb + 4194304);// 128 fp32

    cvt_all<<<14336, 256, 0, stream>>>(x, enc, Q1w, Q2w, K1w, K2w, Vw, outw,
                                       xb, encb, wq, wkv, wob, stats);

    gemm_bf16<0><<<dim3(16, 32), 256, 0, stream>>>(xb,   wq,  Q1b, Q2b, Q2b, q12,  1024);
    gemm_bf16<2><<<dim3(24, 32), 256, 0, stream>>>(encb, wkv, K1b, K2b, Vb,  k12v, 1024);

    diff_attn_mfma<<<dim3(64, 8), 512, 0, stream>>>(q12, k12v, lam, attnb, stats);

    gn_apply<<<2048, 256, 0, stream>>>(attnb, stats, gng, gnb, yb);

    gemm_bf16<1><<<dim3(8, 32), 256, 0, stream>>>(yb, wob, outb, outb, outb, out, 1024);
}

// Round 6
// 283.284 us; speedup vs baseline: 1.1370x; 1.1370x over previous
//
#include <hip/hip_runtime.h>
#include <cmath>

typedef __bf16 bf16_t;
typedef bf16_t bf16x8 __attribute__((ext_vector_type(8)));
typedef bf16_t bf16x4 __attribute__((ext_vector_type(4)));
typedef float  f32x4  __attribute__((ext_vector_type(4)));

#define Bn  4
#define TQn 1024
#define TKn 1024
#define En  1024
#define Hn  16
#define DHn 64

static constexpr float EPSv = 1e-5f;
// softmax in exp2 domain: scale = (1/sqrt(64)) * log2(e)
static constexpr float C_SCALE = 0.18033688011112042f;

#define GLDS16(g, l)                                                         \
    __builtin_amdgcn_global_load_lds(                                        \
        (const __attribute__((address_space(1))) void*)(g),                  \
        (__attribute__((address_space(3))) void*)(l), 16, 0, 0)

// ---------------------------------------------------------------------------
// fp32 -> bf16 conversion, all tensors fused; also zeroes the GN stats accum.
// ---------------------------------------------------------------------------
__global__ __launch_bounds__(256)
void cvt_all(const float* __restrict__ x, const float* __restrict__ enc,
             const float* __restrict__ q1w, const float* __restrict__ q2w,
             const float* __restrict__ k1w, const float* __restrict__ k2w,
             const float* __restrict__ vw,  const float* __restrict__ outw,
             bf16_t* __restrict__ xb, bf16_t* __restrict__ encb,
             bf16_t* __restrict__ wq, bf16_t* __restrict__ wkv,
             bf16_t* __restrict__ wob, float* __restrict__ stats)
{
    if (blockIdx.x == 0 && threadIdx.x < 128) stats[threadIdx.x] = 0.f;
    int idx = blockIdx.x * 256 + threadIdx.x;   // 0 .. 3670015
    const float* src; bf16_t* dst;
    if      (idx < 1048576) { src = x    + (size_t)idx * 4;              dst = xb   + (size_t)idx * 4; }
    else if (idx < 2097152) { src = enc  + (size_t)(idx - 1048576) * 4;  dst = encb + (size_t)(idx - 1048576) * 4; }
    else if (idx < 2359296) { src = q1w  + (size_t)(idx - 2097152) * 4;  dst = wq   + (size_t)(idx - 2097152) * 4; }
    else if (idx < 2621440) { src = q2w  + (size_t)(idx - 2359296) * 4;  dst = wq   + 1048576 + (size_t)(idx - 2359296) * 4; }
    else if (idx < 2883584) { src = k1w  + (size_t)(idx - 2621440) * 4;  dst = wkv  + (size_t)(idx - 2621440) * 4; }
    else if (idx < 3145728) { src = k2w  + (size_t)(idx - 2883584) * 4;  dst = wkv  + 1048576 + (size_t)(idx - 2883584) * 4; }
    else if (idx < 3407872) { src = vw   + (size_t)(idx - 3145728) * 4;  dst = wkv  + 2097152 + (size_t)(idx - 3145728) * 4; }
    else                    { src = outw + (size_t)(idx - 3407872) * 4;  dst = wob  + (size_t)(idx - 3407872) * 4; }
    float4 v = *(const float4*)src;
    bf16x4 o;
    o[0] = (bf16_t)v.x; o[1] = (bf16_t)v.y; o[2] = (bf16_t)v.z; o[3] = (bf16_t)v.w;
    *(bf16x4*)dst = o;
}

// ---------------------------------------------------------------------------
// Merged projection GEMM: all 5 projections in one launch.
// Grid (40, 32): n-blocks 0..15 -> Q1|Q2 (A = xb), 16..39 -> K1|K2|V (A = encb).
// seg = n0>>10 in 0..4. Output: segs 0-3 scatter bf16 [t][d]; seg 4 (V)
// stores transposed [d][t] for the attention kernel's GLDS staging.
// 128x128 tile, BK=64, GLDS16 staging, XOR swizzle, 4 waves 2x2.
// ---------------------------------------------------------------------------
__global__ __launch_bounds__(256, 3)
void gemm_proj(const bf16_t* __restrict__ xb, const bf16_t* __restrict__ encb,
               const bf16_t* __restrict__ wq, const bf16_t* __restrict__ wkv,
               const float* __restrict__ q1b, const float* __restrict__ q2b,
               const float* __restrict__ k1b, const float* __restrict__ k2b,
               const float* __restrict__ vb,
               bf16_t* __restrict__ q12, bf16_t* __restrict__ k12v)
{
    __shared__ bf16_t sA[128 * 64];
    __shared__ bf16_t sB[128 * 64];
    const int tid = threadIdx.x;
    const int w = tid >> 6, lane = tid & 63;
    const int q = lane >> 4, r = lane & 15;
    const int wm = w & 1, wn = w >> 1;
    const int blockM = blockIdx.y * 128, blockN = blockIdx.x * 128;
    const int seg = blockN >> 10;
    const bf16_t* A = (seg < 2) ? xb : encb;
    const bf16_t* W = (seg < 2) ? (wq + (size_t)blockN * 1024)
                                : (wkv + (size_t)(blockN - 2048) * 1024);
    const float* bp = (seg == 0) ? q1b : (seg == 1) ? q2b :
                      (seg == 2) ? k1b : (seg == 3) ? k2b : vb;

    f32x4 acc[4][4];
#pragma unroll
    for (int i = 0; i < 4; ++i)
#pragma unroll
        for (int j = 0; j < 4; ++j) acc[i][j] = (f32x4){0.f, 0.f, 0.f, 0.f};

    for (int k0 = 0; k0 < 1024; k0 += 64) {
#pragma unroll
        for (int c = 0; c < 4; ++c) {
            const int s = c * 256 + tid;
            const int row = s >> 3;
            const int cg = (s & 7) ^ (row & 7);
            GLDS16(A + (size_t)(blockM + row) * 1024 + k0 + cg * 8, sA + c * 2048 + w * 512);
            GLDS16(W + (size_t)row * 1024 + k0 + cg * 8,            sB + c * 2048 + w * 512);
        }
        __syncthreads();
#pragma unroll
        for (int ks = 0; ks < 2; ++ks) {
            bf16x8 a[4], b[4];
#pragma unroll
            for (int i = 0; i < 4; ++i) {
                const int row = wm * 64 + i * 16 + r;
                const int g = (ks * 4 + q) ^ (row & 7);
                a[i] = *(const bf16x8*)&sA[row * 64 + g * 8];
            }
#pragma unroll
            for (int j = 0; j < 4; ++j) {
                const int row = wn * 64 + j * 16 + r;
                const int g = (ks * 4 + q) ^ (row & 7);
                b[j] = *(const bf16x8*)&sB[row * 64 + g * 8];
            }
#pragma unroll
            for (int i = 0; i < 4; ++i)
#pragma unroll
                for (int j = 0; j < 4; ++j)
                    acc[i][j] = __builtin_amdgcn_mfma_f32_16x16x32_bf16(a[i], b[j], acc[i][j], 0, 0, 0);
        }
        __syncthreads();
    }

#pragma unroll
    for (int j = 0; j < 4; ++j) {
        const int n = blockN + wn * 64 + j * 16 + r;
        const int nl = n & 1023;
        const int h = nl >> 6, d = nl & 63;
        const float bv = bp[nl];
#pragma unroll
        for (int i = 0; i < 4; ++i) {
            f32x4 v = acc[i][j];
#pragma unroll
            for (int e = 0; e < 4; ++e) {
                const int m = blockM + wm * 64 + i * 16 + q * 4 + e;
                const int bb = m >> 10, t = m & 1023;
                const float val = v[e] + bv;
                if (seg < 2) {
                    q12[((size_t)(seg * 4 + bb) * 16 + h) * 65536 + (size_t)t * 64 + d] = (bf16_t)val;
                } else if (seg < 4) {
                    k12v[((size_t)((seg - 2) * 4 + bb) * 16 + h) * 65536 + (size_t)t * 64 + d] = (bf16_t)val;
                } else {
                    k12v[((size_t)(8 + bb) * 16 + h) * 65536 + (size_t)d * 1024 + t] = (bf16_t)val;
                }
            }
        }
    }
}

// ---------------------------------------------------------------------------
// Final GEMM: out[m,n] = y[m,:]·outw[n,:] + outb[n], fp32 out [4096,1024]
// ---------------------------------------------------------------------------
__global__ __launch_bounds__(256, 3)
void gemm_out(const bf16_t* __restrict__ A, const bf16_t* __restrict__ W,
              const float* __restrict__ bias, float* __restrict__ C)
{
    __shared__ bf16_t sA[128 * 64];
    __shared__ bf16_t sB[128 * 64];
    const int tid = threadIdx.x;
    const int w = tid >> 6, lane = tid & 63;
    const int q = lane >> 4, r = lane & 15;
    const int wm = w & 1, wn = w >> 1;
    const int blockM = blockIdx.y * 128, blockN = blockIdx.x * 128;

    f32x4 acc[4][4];
#pragma unroll
    for (int i = 0; i < 4; ++i)
#pragma unroll
        for (int j = 0; j < 4; ++j) acc[i][j] = (f32x4){0.f, 0.f, 0.f, 0.f};

    for (int k0 = 0; k0 < 1024; k0 += 64) {
#pragma unroll
        for (int c = 0; c < 4; ++c) {
            const int s = c * 256 + tid;
            const int row = s >> 3;
            const int cg = (s & 7) ^ (row & 7);
            GLDS16(A + (size_t)(blockM + row) * 1024 + k0 + cg * 8, sA + c * 2048 + w * 512);
            GLDS16(W + (size_t)(blockN + row) * 1024 + k0 + cg * 8, sB + c * 2048 + w * 512);
        }
        __syncthreads();
#pragma unroll
        for (int ks = 0; ks < 2; ++ks) {
            bf16x8 a[4], b[4];
#pragma unroll
            for (int i = 0; i < 4; ++i) {
                const int row = wm * 64 + i * 16 + r;
                const int g = (ks * 4 + q) ^ (row & 7);
                a[i] = *(const bf16x8*)&sA[row * 64 + g * 8];
            }
#pragma unroll
            for (int j = 0; j < 4; ++j) {
                const int row = wn * 64 + j * 16 + r;
                const int g = (ks * 4 + q) ^ (row & 7);
                b[j] = *(const bf16x8*)&sB[row * 64 + g * 8];
            }
#pragma unroll
            for (int i = 0; i < 4; ++i)
#pragma unroll
                for (int j = 0; j < 4; ++j)
                    acc[i][j] = __builtin_amdgcn_mfma_f32_16x16x32_bf16(a[i], b[j], acc[i][j], 0, 0, 0);
        }
        __syncthreads();
    }

#pragma unroll
    for (int j = 0; j < 4; ++j) {
        const int n = blockN + wn * 64 + j * 16 + r;
        const float bv = bias[n];
#pragma unroll
        for (int i = 0; i < 4; ++i) {
            f32x4 v = acc[i][j];
#pragma unroll
            for (int e = 0; e < 4; ++e) {
                const int m = blockM + wm * 64 + i * 16 + q * 4 + e;
                C[(size_t)m * 1024 + n] = v[e] + bv;
            }
        }
    }
}

// ---------------------------------------------------------------------------
// Differential flash attention, bf16 MFMA, transposed-S.
// Grid (64, 8): x = bh (XCD-local K/V), y = qt. Block 512 thr = 8 waves,
// each wave owns 16 Q-rows, full 64-wide K-tiles, 16 iterations.
// LDS exactly 40 KB -> with VGPR<=128 (launch_bounds(512,4)):
// 2 blocks/CU = 16 waves/CU = 4 waves/SIMD.
// K1,K2 staged via GLDS from [t][d]; V staged via GLDS from pre-transposed
// [d][t] global (produced by gemm_proj seg 4) — no in-kernel transpose.
// Softmax in exp2 domain, no running max (scores bounded); P round-trips
// the wave-private sPt strip (in-wave write->read, no barrier).
// ---------------------------------------------------------------------------
__global__ __launch_bounds__(512, 4)
void diff_attn_mfma(const bf16_t* __restrict__ q12, const bf16_t* __restrict__ k12v,
                    const float* __restrict__ lam, bf16_t* __restrict__ out,
                    float* __restrict__ stats)
{
    __shared__ bf16_t sK1[64 * 64];    //  8 KB
    __shared__ bf16_t sK2[64 * 64];    //  8 KB
    __shared__ bf16_t sVt[64 * 64];    //  8 KB  [d][s]
    __shared__ bf16_t sPt[128 * 64];   // 16 KB  [t][s], wave-private 16-row strips

    const int tid = threadIdx.x;
    const int w = tid >> 6, lane = tid & 63;
    const int q = lane >> 4, r = lane & 15;
    const int bh = blockIdx.x, qt = blockIdx.y;
    const float lamv = lam[bh & (Hn - 1)];

    const size_t HT = (size_t)TKn * DHn;          // 65536
    const bf16_t* q1g = q12 + (size_t)bh * HT + ((size_t)qt * 128 + w * 16) * 64;
    const bf16_t* q2g = q1g + 64 * HT;
    const bf16_t* k1g = k12v + (size_t)bh * HT;
    const bf16_t* k2g = k1g + 64 * HT;
    const bf16_t* vg  = k12v + (size_t)(128 + bh) * HT;   // V^T: [d][t], row stride 1024

    // Q fragments in registers (B-operand): t = r, k = ks*32 + q*8
    bf16x8 fQ1[2], fQ2[2];
#pragma unroll
    for (int ks = 0; ks < 2; ++ks) {
        fQ1[ks] = *(const bf16x8*)(q1g + (size_t)r * 64 + ks * 32 + q * 8);
        fQ2[ks] = *(const bf16x8*)(q2g + (size_t)r * 64 + ks * 32 + q * 8);
    }

    f32x4 O1[4], O2[4];
    float l1 = 0.f, l2 = 0.f;
#pragma unroll
    for (int j = 0; j < 4; ++j) { O1[j] = (f32x4){0.f,0.f,0.f,0.f}; O2[j] = (f32x4){0.f,0.f,0.f,0.f}; }

    // staging indices: 512 chunks of 16 B, one per thread
    const int srow = tid >> 3;                 // 0..63 (s-row for K, d-row for V)
    const int scg  = (tid & 7) ^ (srow & 7);   // source-address swizzle

    for (int st = 0; st < TKn / 64; ++st) {
        __syncthreads();   // prior tile's readers done
        GLDS16(k1g + (size_t)st * 4096 + srow * 64 + scg * 8, sK1 + w * 512);
        GLDS16(k2g + (size_t)st * 4096 + srow * 64 + scg * 8, sK2 + w * 512);
        GLDS16(vg + (size_t)srow * 1024 + st * 64 + scg * 8,  sVt + w * 512);
        __syncthreads();   // data visible (barrier drains vmcnt)

#pragma unroll
        for (int stream = 0; stream < 2; ++stream) {
            const bf16_t* sK = stream ? sK2 : sK1;
            const bf16x8 (&fQ)[2] = stream ? fQ2 : fQ1;
            f32x4 (&O)[4] = stream ? O2 : O1;

            // S^T[s][t] for this wave's 16 t: A = K rows, B = Q
            f32x4 S[4];
#pragma unroll
            for (int i = 0; i < 4; ++i) S[i] = (f32x4){0.f,0.f,0.f,0.f};
#pragma unroll
            for (int ks = 0; ks < 2; ++ks) {
#pragma unroll
                for (int i = 0; i < 4; ++i) {
                    const int g = (ks * 4 + q) ^ (r & 7);
                    bf16x8 fK = *(const bf16x8*)&sK[(i * 16 + r) * 64 + g * 8];
                    S[i] = __builtin_amdgcn_mfma_f32_16x16x32_bf16(fK, fQ[ks], S[i], 0, 0, 0);
                }
            }
            // exp2 + pack 4 consecutive s into b64 write to wave strip; sum l
            float part = 0.f;
#pragma unroll
            for (int i = 0; i < 4; ++i) {
                bf16x4 pk;
#pragma unroll
                for (int e = 0; e < 4; ++e) {
                    const float p = __builtin_amdgcn_exp2f(S[i][e] * C_SCALE);
                    part += p;
                    pk[e] = (bf16_t)p;
                }
                const int sb = i * 16 + q * 4;
                const int g = (sb >> 3) ^ (r & 7);
                *(bf16x4*)&sPt[(w * 16 + r) * 64 + g * 8 + (sb & 7)] = pk;
            }
            if (stream) l2 += part; else l1 += part;

            // O[t][d] += P·V^T (in-wave strip read; lgkmcnt orders write->read)
#pragma unroll
            for (int ks = 0; ks < 2; ++ks) {
                const int g = (ks * 4 + q) ^ (r & 7);
                bf16x8 fP = *(const bf16x8*)&sPt[(w * 16 + r) * 64 + g * 8];
#pragma unroll
                for (int j = 0; j < 4; ++j) {
                    bf16x8 fV = *(const bf16x8*)&sVt[(j * 16 + r) * 64 + g * 8];
                    O[j] = __builtin_amdgcn_mfma_f32_16x16x32_bf16(fP, fV, O[j], 0, 0, 0);
                }
            }
        }
    }

    // ---- l reduction across q-groups: lanes r, r+16, r+32, r+48 ----
    l1 += __shfl_xor(l1, 16); l1 += __shfl_xor(l1, 32);
    l2 += __shfl_xor(l2, 16); l2 += __shfl_xor(l2, 32);

    // ---- epilogue: out bf16 [bh][t][d] + GN partial sums ----
    bf16_t* op = out + ((size_t)bh * TQn + (size_t)qt * 128 + w * 16) * DHn;
    float ssum = 0.f, ssq = 0.f;
#pragma unroll
    for (int e = 0; e < 4; ++e) {
        const int t_l = q * 4 + e;                 // O C-layout row
        const float inv1 = 1.0f / __shfl(l1, t_l);
        const float inv2 = lamv / __shfl(l2, t_l);
#pragma unroll
        for (int j = 0; j < 4; ++j) {
            const float o = O1[j][e] * inv1 - O2[j][e] * inv2;
            op[(size_t)t_l * 64 + j * 16 + r] = (bf16_t)o;
            ssum += o;
            ssq += o * o;
        }
    }
#pragma unroll
    for (int d = 1; d < 64; d <<= 1) {
        ssum += __shfl_xor(ssum, d);
        ssq  += __shfl_xor(ssq, d);
    }
    if (lane == 0) {
        atomicAdd(&stats[bh], ssum);
        atomicAdd(&stats[64 + bh], ssq);
    }
}

// ---------------------------------------------------------------------------
// GroupNorm apply (mu/rstd from atomic sums) + transpose -> y bf16 [B*T,H*DH]
// ---------------------------------------------------------------------------
__global__ __launch_bounds__(256)
void gn_apply(const bf16_t* __restrict__ attn, const float* __restrict__ stats,
              const float* __restrict__ gamma, const float* __restrict__ beta,
              bf16_t* __restrict__ y)
{
    const int f = blockIdx.x * 256 + threadIdx.x;   // 8-elem group, 0..524287
    const int d8 = (f & 7) << 3;
    const int t  = (f >> 3) & 1023;
    const int bh = f >> 13;
    const int h  = bh & 15;
    const int b  = bh >> 4;
    const float s1 = stats[bh], s2 = stats[64 + bh];
    const float mu = s1 * (1.f / 65536.f);
    const float var = s2 * (1.f / 65536.f) - mu * mu;
    const float rstd = rsqrtf(var + EPSv);
    bf16x8 v = *(const bf16x8*)&attn[((size_t)bh << 16) + t * 64 + d8];
    const int c = h * 64 + d8;
    const float* gp = gamma + c;
    const float* bp = beta + c;
    bf16x8 o;
#pragma unroll
    for (int i = 0; i < 8; ++i)
        o[i] = (bf16_t)(((float)v[i] - mu) * rstd * gp[i] + bp[i]);
    *(bf16x8*)&y[((size_t)(b * 1024 + t)) * 1024 + c] = o;
}

// ---------------------------------------------------------------------------
extern "C" void kernel_launch(void* const* d_in, const int* in_sizes, int n_in,
                              void* d_out, int out_size, void* d_ws, size_t ws_size,
                              hipStream_t stream)
{
    const float* x    = (const float*)d_in[0];
    const float* enc  = (const float*)d_in[1];
    const float* Q1w  = (const float*)d_in[2];
    const float* Q1b  = (const float*)d_in[3];
    const float* Q2w  = (const float*)d_in[4];
    const float* Q2b  = (const float*)d_in[5];
    const float* K1w  = (const float*)d_in[6];
    const float* K1b  = (const float*)d_in[7];
    const float* K2w  = (const float*)d_in[8];
    const float* K2b  = (const float*)d_in[9];
    const float* Vw   = (const float*)d_in[10];
    const float* Vb   = (const float*)d_in[11];
    const float* lam  = (const float*)d_in[12];
    const float* gng  = (const float*)d_in[13];
    const float* gnb  = (const float*)d_in[14];
    const float* outw = (const float*)d_in[15];
    const float* outb = (const float*)d_in[16];
    float* out = (float*)d_out;

    // workspace layout (bf16 elems unless noted)
    bf16_t* xb   = (bf16_t*)d_ws;            // 4,194,304
    bf16_t* encb = xb   + 4194304;           // 4,194,304
    bf16_t* wq   = encb + 4194304;           // 2,097,152  [Q1w|Q2w]
    bf16_t* wkv  = wq   + 2097152;           // 3,145,728  [K1w|K2w|Vw]
    bf16_t* wob  = wkv  + 3145728;           // 1,048,576
    bf16_t* q12  = wob  + 1048576;           // 8,388,608  [2][B][H][T][D]
    bf16_t* k12v = q12  + 8388608;           // 12,582,912 [K1|K2: t,d][V: d,t]
    bf16_t* yb   = k12v + 12582912;          // 4,194,304
    bf16_t* attnb= yb   + 4194304;           // 4,194,304
    float*  stats= (float*)(attnb + 4194304);// 128 fp32

    cvt_all<<<14336, 256, 0, stream>>>(x, enc, Q1w, Q2w, K1w, K2w, Vw, outw,
                                       xb, encb, wq, wkv, wob, stats);

    gemm_proj<<<dim3(40, 32), 256, 0, stream>>>(xb, encb, wq, wkv,
                                                Q1b, Q2b, K1b, K2b, Vb,
                                                q12, k12v);

    diff_attn_mfma<<<dim3(64, 8), 512, 0, stream>>>(q12, k12v, lam, attnb, stats);

    gn_apply<<<2048, 256, 0, stream>>>(attnb, stats, gng, gnb, yb);

    gemm_out<<<dim3(8, 32), 256, 0, stream>>>(yb, wob, outb, out);
}

// Round 7
// 268.819 us; speedup vs baseline: 1.1982x; 1.0538x over previous
//
#include <hip/hip_runtime.h>
#include <cmath>

typedef __bf16 bf16_t;
typedef bf16_t bf16x8 __attribute__((ext_vector_type(8)));
typedef bf16_t bf16x4 __attribute__((ext_vector_type(4)));
typedef float  f32x4  __attribute__((ext_vector_type(4)));

#define Bn  4
#define TQn 1024
#define TKn 1024
#define En  1024
#define Hn  16
#define DHn 64

static constexpr float EPSv = 1e-5f;
// softmax in exp2 domain: scale = (1/sqrt(64)) * log2(e)
static constexpr float C_SCALE = 0.18033688011112042f;

#define GLDS16(g, l)                                                         \
    __builtin_amdgcn_global_load_lds(                                        \
        (const __attribute__((address_space(1))) void*)(g),                  \
        (__attribute__((address_space(3))) void*)(l), 16, 0, 0)

// ---------------------------------------------------------------------------
// fp32 -> bf16 conversion (8 floats/thread), fused; zeroes GN stats accum.
// ---------------------------------------------------------------------------
__global__ __launch_bounds__(256)
void cvt_all(const float* __restrict__ x, const float* __restrict__ enc,
             const float* __restrict__ q1w, const float* __restrict__ q2w,
             const float* __restrict__ k1w, const float* __restrict__ k2w,
             const float* __restrict__ vw,  const float* __restrict__ outw,
             bf16_t* __restrict__ xb, bf16_t* __restrict__ encb,
             bf16_t* __restrict__ wq, bf16_t* __restrict__ wkv,
             bf16_t* __restrict__ wob, float* __restrict__ stats)
{
    if (blockIdx.x == 0 && threadIdx.x < 128) stats[threadIdx.x] = 0.f;
    int idx = blockIdx.x * 256 + threadIdx.x;   // float8 unit, 0..1835007
    const float* src; bf16_t* dst;
    if      (idx <  524288) { src = x    + (size_t)idx * 8;              dst = xb   + (size_t)idx * 8; }
    else if (idx < 1048576) { src = enc  + (size_t)(idx -  524288) * 8;  dst = encb + (size_t)(idx -  524288) * 8; }
    else if (idx < 1179648) { src = q1w  + (size_t)(idx - 1048576) * 8;  dst = wq   + (size_t)(idx - 1048576) * 8; }
    else if (idx < 1310720) { src = q2w  + (size_t)(idx - 1179648) * 8;  dst = wq   + 1048576 + (size_t)(idx - 1179648) * 8; }
    else if (idx < 1441792) { src = k1w  + (size_t)(idx - 1310720) * 8;  dst = wkv  + (size_t)(idx - 1310720) * 8; }
    else if (idx < 1572864) { src = k2w  + (size_t)(idx - 1441792) * 8;  dst = wkv  + 1048576 + (size_t)(idx - 1441792) * 8; }
    else if (idx < 1703936) { src = vw   + (size_t)(idx - 1572864) * 8;  dst = wkv  + 2097152 + (size_t)(idx - 1572864) * 8; }
    else                    { src = outw + (size_t)(idx - 1703936) * 8;  dst = wob  + (size_t)(idx - 1703936) * 8; }
    float4 a = *(const float4*)src;
    float4 b = *(const float4*)(src + 4);
    bf16x8 o;
    o[0] = (bf16_t)a.x; o[1] = (bf16_t)a.y; o[2] = (bf16_t)a.z; o[3] = (bf16_t)a.w;
    o[4] = (bf16_t)b.x; o[5] = (bf16_t)b.y; o[6] = (bf16_t)b.z; o[7] = (bf16_t)b.w;
    *(bf16x8*)dst = o;
}

// ---------------------------------------------------------------------------
// Merged projection GEMM: all 5 projections in one launch.
// Grid (40, 32): n-blocks 0..15 -> Q1|Q2 (A = xb), 16..39 -> K1|K2|V (A = encb).
// seg = n0>>10 in 0..4. segs 0-3: bf16 [t][d]; seg 4 (V): transposed [d][t].
// Epilogue repacks C through the freed sA/sB LDS into coalesced bf16x8 stores.
// 128x128 tile, BK=64, GLDS16 staging, XOR swizzle, 4 waves 2x2, 4 blocks/CU.
// ---------------------------------------------------------------------------
__global__ __launch_bounds__(256, 4)
void gemm_proj(const bf16_t* __restrict__ xb, const bf16_t* __restrict__ encb,
               const bf16_t* __restrict__ wq, const bf16_t* __restrict__ wkv,
               const float* __restrict__ q1b, const float* __restrict__ q2b,
               const float* __restrict__ k1b, const float* __restrict__ k2b,
               const float* __restrict__ vb,
               bf16_t* __restrict__ q12, bf16_t* __restrict__ k12v)
{
    __shared__ bf16_t sA[128 * 64];
    __shared__ bf16_t sB[128 * 64];
    const int tid = threadIdx.x;
    const int w = tid >> 6, lane = tid & 63;
    const int q = lane >> 4, r = lane & 15;
    const int wm = w & 1, wn = w >> 1;
    const int blockM = blockIdx.y * 128, blockN = blockIdx.x * 128;
    const int seg = blockN >> 10;
    const bf16_t* A = (seg < 2) ? xb : encb;
    const bf16_t* W = (seg < 2) ? (wq + (size_t)blockN * 1024)
                                : (wkv + (size_t)(blockN - 2048) * 1024);
    const float* bp = (seg == 0) ? q1b : (seg == 1) ? q2b :
                      (seg == 2) ? k1b : (seg == 3) ? k2b : vb;

    f32x4 acc[4][4];
#pragma unroll
    for (int i = 0; i < 4; ++i)
#pragma unroll
        for (int j = 0; j < 4; ++j) acc[i][j] = (f32x4){0.f, 0.f, 0.f, 0.f};

    for (int k0 = 0; k0 < 1024; k0 += 64) {
#pragma unroll
        for (int c = 0; c < 4; ++c) {
            const int s = c * 256 + tid;
            const int row = s >> 3;
            const int cg = (s & 7) ^ (row & 7);
            GLDS16(A + (size_t)(blockM + row) * 1024 + k0 + cg * 8, sA + c * 2048 + w * 512);
            GLDS16(W + (size_t)row * 1024 + k0 + cg * 8,            sB + c * 2048 + w * 512);
        }
        __syncthreads();
#pragma unroll
        for (int ks = 0; ks < 2; ++ks) {
            bf16x8 a[4], b[4];
#pragma unroll
            for (int i = 0; i < 4; ++i) {
                const int row = wm * 64 + i * 16 + r;
                const int g = (ks * 4 + q) ^ (row & 7);
                a[i] = *(const bf16x8*)&sA[row * 64 + g * 8];
            }
#pragma unroll
            for (int j = 0; j < 4; ++j) {
                const int row = wn * 64 + j * 16 + r;
                const int g = (ks * 4 + q) ^ (row & 7);
                b[j] = *(const bf16x8*)&sB[row * 64 + g * 8];
            }
#pragma unroll
            for (int i = 0; i < 4; ++i)
#pragma unroll
                for (int j = 0; j < 4; ++j)
                    acc[i][j] = __builtin_amdgcn_mfma_f32_16x16x32_bf16(a[i], b[j], acc[i][j], 0, 0, 0);
        }
        __syncthreads();
    }

    // ---- epilogue: bias, repack via wave-private LDS strip, coalesced store
    float bv[4];
#pragma unroll
    for (int j = 0; j < 4; ++j)
        bv[j] = bp[(blockN + wn * 64 + j * 16 + r) & 1023];

    bf16_t* rep = ((w & 2) ? sB : sA) + (w & 1) * 4096;   // 64x64 bf16 per wave
    if (seg < 4) {           // [t_loc][d_loc]
#pragma unroll
        for (int i = 0; i < 4; ++i)
#pragma unroll
            for (int j = 0; j < 4; ++j)
#pragma unroll
                for (int e = 0; e < 4; ++e)
                    rep[(i * 16 + q * 4 + e) * 64 + j * 16 + r] = (bf16_t)(acc[i][j][e] + bv[j]);
    } else {                 // [d_loc][t_loc] (transposed for V^T)
#pragma unroll
        for (int i = 0; i < 4; ++i)
#pragma unroll
            for (int j = 0; j < 4; ++j)
#pragma unroll
                for (int e = 0; e < 4; ++e)
                    rep[(j * 16 + r) * 64 + i * 16 + q * 4 + e] = (bf16_t)(acc[i][j][e] + bv[j]);
    }
    // wave-private strip: in-wave write->read ordering via lgkmcnt, no barrier
    const int rrow = lane >> 3, rcol = (lane & 7) * 8;
#pragma unroll
    for (int t8 = 0; t8 < 8; ++t8) {
        const int row = t8 * 8 + rrow;
        bf16x8 v = *(const bf16x8*)&rep[row * 64 + rcol];
        if (seg < 4) {
            const int m = blockM + wm * 64 + row;
            const int bb = m >> 10, t = m & 1023;
            const int n = blockN + wn * 64 + rcol;
            const int h = (n >> 6) & 15, d = n & 63;
            bf16_t* dst = (seg < 2)
                ? q12  + ((size_t)(seg * 4 + bb) * 16 + h) * 65536 + (size_t)t * 64 + d
                : k12v + ((size_t)((seg - 2) * 4 + bb) * 16 + h) * 65536 + (size_t)t * 64 + d;
            *(bf16x8*)dst = v;
        } else {
            const int n = blockN + wn * 64 + row;        // d-row
            const int h = (n >> 6) & 15, d = n & 63;
            const int m = blockM + wm * 64 + rcol;
            const int bb = m >> 10, t = m & 1023;
            *(bf16x8*)(k12v + ((size_t)(8 + bb) * 16 + h) * 65536 + (size_t)d * 1024 + t) = v;
        }
    }
}

// ---------------------------------------------------------------------------
// Final GEMM: out[m,n] = y[m,:]·outw[n,:] + outb[n], fp32 out [4096,1024]
// ---------------------------------------------------------------------------
__global__ __launch_bounds__(256, 4)
void gemm_out(const bf16_t* __restrict__ A, const bf16_t* __restrict__ W,
              const float* __restrict__ bias, float* __restrict__ C)
{
    __shared__ bf16_t sA[128 * 64];
    __shared__ bf16_t sB[128 * 64];
    const int tid = threadIdx.x;
    const int w = tid >> 6, lane = tid & 63;
    const int q = lane >> 4, r = lane & 15;
    const int wm = w & 1, wn = w >> 1;
    const int blockM = blockIdx.y * 128, blockN = blockIdx.x * 128;

    f32x4 acc[4][4];
#pragma unroll
    for (int i = 0; i < 4; ++i)
#pragma unroll
        for (int j = 0; j < 4; ++j) acc[i][j] = (f32x4){0.f, 0.f, 0.f, 0.f};

    for (int k0 = 0; k0 < 1024; k0 += 64) {
#pragma unroll
        for (int c = 0; c < 4; ++c) {
            const int s = c * 256 + tid;
            const int row = s >> 3;
            const int cg = (s & 7) ^ (row & 7);
            GLDS16(A + (size_t)(blockM + row) * 1024 + k0 + cg * 8, sA + c * 2048 + w * 512);
            GLDS16(W + (size_t)(blockN + row) * 1024 + k0 + cg * 8, sB + c * 2048 + w * 512);
        }
        __syncthreads();
#pragma unroll
        for (int ks = 0; ks < 2; ++ks) {
            bf16x8 a[4], b[4];
#pragma unroll
            for (int i = 0; i < 4; ++i) {
                const int row = wm * 64 + i * 16 + r;
                const int g = (ks * 4 + q) ^ (row & 7);
                a[i] = *(const bf16x8*)&sA[row * 64 + g * 8];
            }
#pragma unroll
            for (int j = 0; j < 4; ++j) {
                const int row = wn * 64 + j * 16 + r;
                const int g = (ks * 4 + q) ^ (row & 7);
                b[j] = *(const bf16x8*)&sB[row * 64 + g * 8];
            }
#pragma unroll
            for (int i = 0; i < 4; ++i)
#pragma unroll
                for (int j = 0; j < 4; ++j)
                    acc[i][j] = __builtin_amdgcn_mfma_f32_16x16x32_bf16(a[i], b[j], acc[i][j], 0, 0, 0);
        }
        __syncthreads();
    }

#pragma unroll
    for (int j = 0; j < 4; ++j) {
        const int n = blockN + wn * 64 + j * 16 + r;
        const float bv = bias[n];
#pragma unroll
        for (int i = 0; i < 4; ++i) {
            f32x4 v = acc[i][j];
#pragma unroll
            for (int e = 0; e < 4; ++e) {
                const int m = blockM + wm * 64 + i * 16 + q * 4 + e;
                C[(size_t)m * 1024 + n] = v[e] + bv;
            }
        }
    }
}

// ---------------------------------------------------------------------------
// Differential flash attention, bf16 MFMA, transposed-S.
// Grid (64, 8): x = bh (XCD-local K/V), y = qt. Block 512 thr = 8 waves,
// each wave owns 16 Q-rows, full 64-wide K-tiles, 16 iterations.
// Per-stream P strips (sP1/sP2) allow a merged PV loop so fV fragments are
// loaded ONCE per (ks,j), shared by both streams: DS/tile/wave 384->288 cy.
// LDS 56 KB -> 2 blocks/CU = 16 waves/CU = 4 waves/SIMD (VGPR<=128).
// ---------------------------------------------------------------------------
__global__ __launch_bounds__(512, 4)
void diff_attn_mfma(const bf16_t* __restrict__ q12, const bf16_t* __restrict__ k12v,
                    const float* __restrict__ lam, bf16_t* __restrict__ out,
                    float* __restrict__ stats)
{
    __shared__ bf16_t sK1[64 * 64];    //  8 KB
    __shared__ bf16_t sK2[64 * 64];    //  8 KB
    __shared__ bf16_t sVt[64 * 64];    //  8 KB  [d][s]
    __shared__ bf16_t sP [8 * 2048];   // 32 KB  per-wave: [stream][16 t][64 s]

    const int tid = threadIdx.x;
    const int w = tid >> 6, lane = tid & 63;
    const int q = lane >> 4, r = lane & 15;
    const int bh = blockIdx.x, qt = blockIdx.y;
    const float lamv = lam[bh & (Hn - 1)];

    bf16_t* sP1 = sP + w * 2048;
    bf16_t* sP2 = sP1 + 1024;

    const size_t HT = (size_t)TKn * DHn;          // 65536
    const bf16_t* q1g = q12 + (size_t)bh * HT + ((size_t)qt * 128 + w * 16) * 64;
    const bf16_t* q2g = q1g + 64 * HT;
    const bf16_t* k1g = k12v + (size_t)bh * HT;
    const bf16_t* k2g = k1g + 64 * HT;
    const bf16_t* vg  = k12v + (size_t)(128 + bh) * HT;   // V^T: [d][t]

    // Q fragments in registers (B-operand): t = r, k = ks*32 + q*8
    bf16x8 fQ1[2], fQ2[2];
#pragma unroll
    for (int ks = 0; ks < 2; ++ks) {
        fQ1[ks] = *(const bf16x8*)(q1g + (size_t)r * 64 + ks * 32 + q * 8);
        fQ2[ks] = *(const bf16x8*)(q2g + (size_t)r * 64 + ks * 32 + q * 8);
    }

    f32x4 O1[4], O2[4];
    float l1 = 0.f, l2 = 0.f;
#pragma unroll
    for (int j = 0; j < 4; ++j) { O1[j] = (f32x4){0.f,0.f,0.f,0.f}; O2[j] = (f32x4){0.f,0.f,0.f,0.f}; }

    // staging indices: 512 chunks of 16 B, one per thread
    const int srow = tid >> 3;                 // 0..63
    const int scg  = (tid & 7) ^ (srow & 7);   // source-address swizzle

    for (int st = 0; st < TKn / 64; ++st) {
        __syncthreads();   // prior tile's readers done
        GLDS16(k1g + (size_t)st * 4096 + srow * 64 + scg * 8, sK1 + w * 512);
        GLDS16(k2g + (size_t)st * 4096 + srow * 64 + scg * 8, sK2 + w * 512);
        GLDS16(vg + (size_t)srow * 1024 + st * 64 + scg * 8,  sVt + w * 512);
        __syncthreads();   // data visible (barrier drains vmcnt)

        // ---- S^T + exp2 + P-write for both streams ----
#pragma unroll
        for (int stream = 0; stream < 2; ++stream) {
            const bf16_t* sK = stream ? sK2 : sK1;
            const bf16x8* fQ = stream ? fQ2 : fQ1;
            bf16_t* sPw = stream ? sP2 : sP1;

            f32x4 S[4];
#pragma unroll
            for (int i = 0; i < 4; ++i) S[i] = (f32x4){0.f,0.f,0.f,0.f};
#pragma unroll
            for (int ks = 0; ks < 2; ++ks) {
#pragma unroll
                for (int i = 0; i < 4; ++i) {
                    const int g = (ks * 4 + q) ^ (r & 7);
                    bf16x8 fK = *(const bf16x8*)&sK[(i * 16 + r) * 64 + g * 8];
                    S[i] = __builtin_amdgcn_mfma_f32_16x16x32_bf16(fK, fQ[ks], S[i], 0, 0, 0);
                }
            }
            float part = 0.f;
#pragma unroll
            for (int i = 0; i < 4; ++i) {
                bf16x4 pk;
#pragma unroll
                for (int e = 0; e < 4; ++e) {
                    const float p = __builtin_amdgcn_exp2f(S[i][e] * C_SCALE);
                    part += p;
                    pk[e] = (bf16_t)p;
                }
                const int sb = i * 16 + q * 4;
                const int g = (sb >> 3) ^ (r & 7);
                *(bf16x4*)&sPw[r * 64 + g * 8 + (sb & 7)] = pk;
            }
            if (stream) l2 += part; else l1 += part;
        }

        // ---- merged PV: fV loaded once, shared by both streams ----
#pragma unroll
        for (int ks = 0; ks < 2; ++ks) {
            const int g = (ks * 4 + q) ^ (r & 7);
            bf16x8 fP1 = *(const bf16x8*)&sP1[r * 64 + g * 8];
            bf16x8 fP2 = *(const bf16x8*)&sP2[r * 64 + g * 8];
#pragma unroll
            for (int j = 0; j < 4; ++j) {
                bf16x8 fV = *(const bf16x8*)&sVt[(j * 16 + r) * 64 + g * 8];
                O1[j] = __builtin_amdgcn_mfma_f32_16x16x32_bf16(fP1, fV, O1[j], 0, 0, 0);
                O2[j] = __builtin_amdgcn_mfma_f32_16x16x32_bf16(fP2, fV, O2[j], 0, 0, 0);
            }
        }
    }

    // ---- l reduction across q-groups: lanes r, r+16, r+32, r+48 ----
    l1 += __shfl_xor(l1, 16); l1 += __shfl_xor(l1, 32);
    l2 += __shfl_xor(l2, 16); l2 += __shfl_xor(l2, 32);

    // ---- epilogue: out bf16 [bh][t][d] + GN partial sums ----
    bf16_t* op = out + ((size_t)bh * TQn + (size_t)qt * 128 + w * 16) * DHn;
    float ssum = 0.f, ssq = 0.f;
#pragma unroll
    for (int e = 0; e < 4; ++e) {
        const int t_l = q * 4 + e;                 // O C-layout row
        const float inv1 = 1.0f / __shfl(l1, t_l);
        const float inv2 = lamv / __shfl(l2, t_l);
#pragma unroll
        for (int j = 0; j < 4; ++j) {
            const float o = O1[j][e] * inv1 - O2[j][e] * inv2;
            op[(size_t)t_l * 64 + j * 16 + r] = (bf16_t)o;
            ssum += o;
            ssq += o * o;
        }
    }
#pragma unroll
    for (int d = 1; d < 64; d <<= 1) {
        ssum += __shfl_xor(ssum, d);
        ssq  += __shfl_xor(ssq, d);
    }
    if (lane == 0) {
        atomicAdd(&stats[bh], ssum);
        atomicAdd(&stats[64 + bh], ssq);
    }
}

// ---------------------------------------------------------------------------
// GroupNorm apply (mu/rstd from atomic sums) + transpose -> y bf16 [B*T,H*DH]
// ---------------------------------------------------------------------------
__global__ __launch_bounds__(256)
void gn_apply(const bf16_t* __restrict__ attn, const float* __restrict__ stats,
              const float* __restrict__ gamma, const float* __restrict__ beta,
              bf16_t* __restrict__ y)
{
    const int f = blockIdx.x * 256 + threadIdx.x;   // 8-elem group, 0..524287
    const int d8 = (f & 7) << 3;
    const int t  = (f >> 3) & 1023;
    const int bh = f >> 13;
    const int h  = bh & 15;
    const int b  = bh >> 4;
    const float s1 = stats[bh], s2 = stats[64 + bh];
    const float mu = s1 * (1.f / 65536.f);
    const float var = s2 * (1.f / 65536.f) - mu * mu;
    const float rstd = rsqrtf(var + EPSv);
    bf16x8 v = *(const bf16x8*)&attn[((size_t)bh << 16) + t * 64 + d8];
    const int c = h * 64 + d8;
    const float* gp = gamma + c;
    const float* bp = beta + c;
    bf16x8 o;
#pragma unroll
    for (int i = 0; i < 8; ++i)
        o[i] = (bf16_t)(((float)v[i] - mu) * rstd * gp[i] + bp[i]);
    *(bf16x8*)&y[((size_t)(b * 1024 + t)) * 1024 + c] = o;
}

// ---------------------------------------------------------------------------
extern "C" void kernel_launch(void* const* d_in, const int* in_sizes, int n_in,
                              void* d_out, int out_size, void* d_ws, size_t ws_size,
                              hipStream_t stream)
{
    const float* x    = (const float*)d_in[0];
    const float* enc  = (const float*)d_in[1];
    const float* Q1w  = (const float*)d_in[2];
    const float* Q1b  = (const float*)d_in[3];
    const float* Q2w  = (const float*)d_in[4];
    const float* Q2b  = (const float*)d_in[5];
    const float* K1w  = (const float*)d_in[6];
    const float* K1b  = (const float*)d_in[7];
    const float* K2w  = (const float*)d_in[8];
    const float* K2b  = (const float*)d_in[9];
    const float* Vw   = (const float*)d_in[10];
    const float* Vb   = (const float*)d_in[11];
    const float* lam  = (const float*)d_in[12];
    const float* gng  = (const float*)d_in[13];
    const float* gnb  = (const float*)d_in[14];
    const float* outw = (const float*)d_in[15];
    const float* outb = (const float*)d_in[16];
    float* out = (float*)d_out;

    // workspace layout (bf16 elems unless noted)
    bf16_t* xb   = (bf16_t*)d_ws;            // 4,194,304
    bf16_t* encb = xb   + 4194304;           // 4,194,304
    bf16_t* wq   = encb + 4194304;           // 2,097,152  [Q1w|Q2w]
    bf16_t* wkv  = wq   + 2097152;           // 3,145,728  [K1w|K2w|Vw]
    bf16_t* wob  = wkv  + 3145728;           // 1,048,576
    bf16_t* q12  = wob  + 1048576;           // 8,388,608  [2][B][H][T][D]
    bf16_t* k12v = q12  + 8388608;           // 12,582,912 [K1|K2: t,d][V: d,t]
    bf16_t* yb   = k12v + 12582912;          // 4,194,304
    bf16_t* attnb= yb   + 4194304;           // 4,194,304
    float*  stats= (float*)(attnb + 4194304);// 128 fp32

    cvt_all<<<7168, 256, 0, stream>>>(x, enc, Q1w, Q2w, K1w, K2w, Vw, outw,
                                      xb, encb, wq, wkv, wob, stats);

    gemm_proj<<<dim3(40, 32), 256, 0, stream>>>(xb, encb, wq, wkv,
                                                Q1b, Q2b, K1b, K2b, Vb,
                                                q12, k12v);

    diff_attn_mfma<<<dim3(64, 8), 512, 0, stream>>>(q12, k12v, lam, attnb, stats);

    gn_apply<<<2048, 256, 0, stream>>>(attnb, stats, gng, gnb, yb);

    gemm_out<<<dim3(8, 32), 256, 0, stream>>>(yb, wob, outb, out);
}

// Round 8
// 264.235 us; speedup vs baseline: 1.2190x; 1.0173x over previous
//
#include <hip/hip_runtime.h>
#include <cmath>

typedef __bf16 bf16_t;
typedef bf16_t bf16x8 __attribute__((ext_vector_type(8)));
typedef bf16_t bf16x4 __attribute__((ext_vector_type(4)));
typedef float  f32x4  __attribute__((ext_vector_type(4)));

#define Bn  4
#define TQn 1024
#define TKn 1024
#define En  1024
#define Hn  16
#define DHn 64

static constexpr float EPSv = 1e-5f;
// softmax in exp2 domain: scale = (1/sqrt(64)) * log2(e)
static constexpr float C_SCALE = 0.18033688011112042f;

#define GLDS16(g, l)                                                         \
    __builtin_amdgcn_global_load_lds(                                        \
        (const __attribute__((address_space(1))) void*)(g),                  \
        (__attribute__((address_space(3))) void*)(l), 16, 0, 0)

// ---------------------------------------------------------------------------
// fp32 -> bf16 conversion (8 floats/thread), fused; zeroes GN stats accum.
// ---------------------------------------------------------------------------
__global__ __launch_bounds__(256)
void cvt_all(const float* __restrict__ x, const float* __restrict__ enc,
             const float* __restrict__ q1w, const float* __restrict__ q2w,
             const float* __restrict__ k1w, const float* __restrict__ k2w,
             const float* __restrict__ vw,  const float* __restrict__ outw,
             bf16_t* __restrict__ xb, bf16_t* __restrict__ encb,
             bf16_t* __restrict__ wq, bf16_t* __restrict__ wkv,
             bf16_t* __restrict__ wob, float* __restrict__ stats)
{
    if (blockIdx.x == 0 && threadIdx.x < 128) stats[threadIdx.x] = 0.f;
    int idx = blockIdx.x * 256 + threadIdx.x;   // float8 unit, 0..1835007
    const float* src; bf16_t* dst;
    if      (idx <  524288) { src = x    + (size_t)idx * 8;              dst = xb   + (size_t)idx * 8; }
    else if (idx < 1048576) { src = enc  + (size_t)(idx -  524288) * 8;  dst = encb + (size_t)(idx -  524288) * 8; }
    else if (idx < 1179648) { src = q1w  + (size_t)(idx - 1048576) * 8;  dst = wq   + (size_t)(idx - 1048576) * 8; }
    else if (idx < 1310720) { src = q2w  + (size_t)(idx - 1179648) * 8;  dst = wq   + 1048576 + (size_t)(idx - 1179648) * 8; }
    else if (idx < 1441792) { src = k1w  + (size_t)(idx - 1310720) * 8;  dst = wkv  + (size_t)(idx - 1310720) * 8; }
    else if (idx < 1572864) { src = k2w  + (size_t)(idx - 1441792) * 8;  dst = wkv  + 1048576 + (size_t)(idx - 1441792) * 8; }
    else if (idx < 1703936) { src = vw   + (size_t)(idx - 1572864) * 8;  dst = wkv  + 2097152 + (size_t)(idx - 1572864) * 8; }
    else                    { src = outw + (size_t)(idx - 1703936) * 8;  dst = wob  + (size_t)(idx - 1703936) * 8; }
    float4 a = *(const float4*)src;
    float4 b = *(const float4*)(src + 4);
    bf16x8 o;
    o[0] = (bf16_t)a.x; o[1] = (bf16_t)a.y; o[2] = (bf16_t)a.z; o[3] = (bf16_t)a.w;
    o[4] = (bf16_t)b.x; o[5] = (bf16_t)b.y; o[6] = (bf16_t)b.z; o[7] = (bf16_t)b.w;
    *(bf16x8*)dst = o;
}

// ---------------------------------------------------------------------------
// Merged projection GEMM: all 5 projections in one launch.
// Grid (40, 32): n-blocks 0..15 -> Q1|Q2 (A = xb), 16..39 -> K1|K2|V (A = encb).
// seg = n0>>10 in 0..4. segs 0-3: bf16 [t][d]; seg 4 (V): transposed [d][t].
// Epilogue repacks C through the freed sA/sB LDS into coalesced bf16x8 stores.
// ---------------------------------------------------------------------------
__global__ __launch_bounds__(256, 4)
void gemm_proj(const bf16_t* __restrict__ xb, const bf16_t* __restrict__ encb,
               const bf16_t* __restrict__ wq, const bf16_t* __restrict__ wkv,
               const float* __restrict__ q1b, const float* __restrict__ q2b,
               const float* __restrict__ k1b, const float* __restrict__ k2b,
               const float* __restrict__ vb,
               bf16_t* __restrict__ q12, bf16_t* __restrict__ k12v)
{
    __shared__ bf16_t sA[128 * 64];
    __shared__ bf16_t sB[128 * 64];
    const int tid = threadIdx.x;
    const int w = tid >> 6, lane = tid & 63;
    const int q = lane >> 4, r = lane & 15;
    const int wm = w & 1, wn = w >> 1;
    const int blockM = blockIdx.y * 128, blockN = blockIdx.x * 128;
    const int seg = blockN >> 10;
    const bf16_t* A = (seg < 2) ? xb : encb;
    const bf16_t* W = (seg < 2) ? (wq + (size_t)blockN * 1024)
                                : (wkv + (size_t)(blockN - 2048) * 1024);
    const float* bp = (seg == 0) ? q1b : (seg == 1) ? q2b :
                      (seg == 2) ? k1b : (seg == 3) ? k2b : vb;

    f32x4 acc[4][4];
#pragma unroll
    for (int i = 0; i < 4; ++i)
#pragma unroll
        for (int j = 0; j < 4; ++j) acc[i][j] = (f32x4){0.f, 0.f, 0.f, 0.f};

    for (int k0 = 0; k0 < 1024; k0 += 64) {
#pragma unroll
        for (int c = 0; c < 4; ++c) {
            const int s = c * 256 + tid;
            const int row = s >> 3;
            const int cg = (s & 7) ^ (row & 7);
            GLDS16(A + (size_t)(blockM + row) * 1024 + k0 + cg * 8, sA + c * 2048 + w * 512);
            GLDS16(W + (size_t)row * 1024 + k0 + cg * 8,            sB + c * 2048 + w * 512);
        }
        __syncthreads();
#pragma unroll
        for (int ks = 0; ks < 2; ++ks) {
            bf16x8 a[4], b[4];
#pragma unroll
            for (int i = 0; i < 4; ++i) {
                const int row = wm * 64 + i * 16 + r;
                const int g = (ks * 4 + q) ^ (row & 7);
                a[i] = *(const bf16x8*)&sA[row * 64 + g * 8];
            }
#pragma unroll
            for (int j = 0; j < 4; ++j) {
                const int row = wn * 64 + j * 16 + r;
                const int g = (ks * 4 + q) ^ (row & 7);
                b[j] = *(const bf16x8*)&sB[row * 64 + g * 8];
            }
#pragma unroll
            for (int i = 0; i < 4; ++i)
#pragma unroll
                for (int j = 0; j < 4; ++j)
                    acc[i][j] = __builtin_amdgcn_mfma_f32_16x16x32_bf16(a[i], b[j], acc[i][j], 0, 0, 0);
        }
        __syncthreads();
    }

    float bv[4];
#pragma unroll
    for (int j = 0; j < 4; ++j)
        bv[j] = bp[(blockN + wn * 64 + j * 16 + r) & 1023];

    bf16_t* rep = ((w & 2) ? sB : sA) + (w & 1) * 4096;   // 64x64 bf16 per wave
    if (seg < 4) {           // [t_loc][d_loc]
#pragma unroll
        for (int i = 0; i < 4; ++i)
#pragma unroll
            for (int j = 0; j < 4; ++j)
#pragma unroll
                for (int e = 0; e < 4; ++e)
                    rep[(i * 16 + q * 4 + e) * 64 + j * 16 + r] = (bf16_t)(acc[i][j][e] + bv[j]);
    } else {                 // [d_loc][t_loc] (transposed for V^T)
#pragma unroll
        for (int i = 0; i < 4; ++i)
#pragma unroll
            for (int j = 0; j < 4; ++j)
#pragma unroll
                for (int e = 0; e < 4; ++e)
                    rep[(j * 16 + r) * 64 + i * 16 + q * 4 + e] = (bf16_t)(acc[i][j][e] + bv[j]);
    }
    const int rrow = lane >> 3, rcol = (lane & 7) * 8;
#pragma unroll
    for (int t8 = 0; t8 < 8; ++t8) {
        const int row = t8 * 8 + rrow;
        bf16x8 v = *(const bf16x8*)&rep[row * 64 + rcol];
        if (seg < 4) {
            const int m = blockM + wm * 64 + row;
            const int bb = m >> 10, t = m & 1023;
            const int n = blockN + wn * 64 + rcol;
            const int h = (n >> 6) & 15, d = n & 63;
            bf16_t* dst = (seg < 2)
                ? q12  + ((size_t)(seg * 4 + bb) * 16 + h) * 65536 + (size_t)t * 64 + d
                : k12v + ((size_t)((seg - 2) * 4 + bb) * 16 + h) * 65536 + (size_t)t * 64 + d;
            *(bf16x8*)dst = v;
        } else {
            const int n = blockN + wn * 64 + row;        // d-row
            const int h = (n >> 6) & 15, d = n & 63;
            const int m = blockM + wm * 64 + rcol;
            const int bb = m >> 10, t = m & 1023;
            *(bf16x8*)(k12v + ((size_t)(8 + bb) * 16 + h) * 65536 + (size_t)d * 1024 + t) = v;
        }
    }
}

// ---------------------------------------------------------------------------
// Final GEMM: out[m,n] = y[m,:]·outw[n,:] + outb[n], fp32 out [4096,1024]
// ---------------------------------------------------------------------------
__global__ __launch_bounds__(256, 4)
void gemm_out(const bf16_t* __restrict__ A, const bf16_t* __restrict__ W,
              const float* __restrict__ bias, float* __restrict__ C)
{
    __shared__ bf16_t sA[128 * 64];
    __shared__ bf16_t sB[128 * 64];
    const int tid = threadIdx.x;
    const int w = tid >> 6, lane = tid & 63;
    const int q = lane >> 4, r = lane & 15;
    const int wm = w & 1, wn = w >> 1;
    const int blockM = blockIdx.y * 128, blockN = blockIdx.x * 128;

    f32x4 acc[4][4];
#pragma unroll
    for (int i = 0; i < 4; ++i)
#pragma unroll
        for (int j = 0; j < 4; ++j) acc[i][j] = (f32x4){0.f, 0.f, 0.f, 0.f};

    for (int k0 = 0; k0 < 1024; k0 += 64) {
#pragma unroll
        for (int c = 0; c < 4; ++c) {
            const int s = c * 256 + tid;
            const int row = s >> 3;
            const int cg = (s & 7) ^ (row & 7);
            GLDS16(A + (size_t)(blockM + row) * 1024 + k0 + cg * 8, sA + c * 2048 + w * 512);
            GLDS16(W + (size_t)(blockN + row) * 1024 + k0 + cg * 8, sB + c * 2048 + w * 512);
        }
        __syncthreads();
#pragma unroll
        for (int ks = 0; ks < 2; ++ks) {
            bf16x8 a[4], b[4];
#pragma unroll
            for (int i = 0; i < 4; ++i) {
                const int row = wm * 64 + i * 16 + r;
                const int g = (ks * 4 + q) ^ (row & 7);
                a[i] = *(const bf16x8*)&sA[row * 64 + g * 8];
            }
#pragma unroll
            for (int j = 0; j < 4; ++j) {
                const int row = wn * 64 + j * 16 + r;
                const int g = (ks * 4 + q) ^ (row & 7);
                b[j] = *(const bf16x8*)&sB[row * 64 + g * 8];
            }
#pragma unroll
            for (int i = 0; i < 4; ++i)
#pragma unroll
                for (int j = 0; j < 4; ++j)
                    acc[i][j] = __builtin_amdgcn_mfma_f32_16x16x32_bf16(a[i], b[j], acc[i][j], 0, 0, 0);
        }
        __syncthreads();
    }

#pragma unroll
    for (int j = 0; j < 4; ++j) {
        const int n = blockN + wn * 64 + j * 16 + r;
        const float bv = bias[n];
#pragma unroll
        for (int i = 0; i < 4; ++i) {
            f32x4 v = acc[i][j];
#pragma unroll
            for (int e = 0; e < 4; ++e) {
                const int m = blockM + wm * 64 + i * 16 + q * 4 + e;
                C[(size_t)m * 1024 + n] = v[e] + bv;
            }
        }
    }
}

// ---------------------------------------------------------------------------
// Differential flash attention, bf16 MFMA, (stream × s-half × t-half) waves.
// Grid (64 bh, 16 qt): Q-tile 64 rows. Block 512 thr = 8 waves:
//   strm = w&1, shalf = (w>>1)&1, thalf = w>>2.
// Each wave: 32 t-rows, one stream, one 32-wide s-half of each 64-s K-tile.
// Exp2-domain softmax without running max -> s-partials add exactly; O and l
// merged across the 4 (strm,shalf) waves per t-half through LDS at the end,
// fused with the GroupNorm partial-sum epilogue.
// LDS 44 KB; __launch_bounds__(512,2) targets 128-VGPR cap (2 blocks/CU,
// 16 waves/CU = 4/SIMD) per the observed toolchain semantics (R5/R7: (512,4)
// produced a 64-VGPR cap).
// ---------------------------------------------------------------------------
__global__ __launch_bounds__(512, 2)
void diff_attn_mfma(const bf16_t* __restrict__ q12, const bf16_t* __restrict__ k12v,
                    const float* __restrict__ lam, bf16_t* __restrict__ out,
                    float* __restrict__ stats)
{
    // bytes: sK1 [0,8K) | sK2 [8K,16K) | sVt [16K,24K) | sP [24K,44K)
    __shared__ __align__(16) bf16_t smem[22528];   // 45,056 B

    const int tid = threadIdx.x;
    const int w = tid >> 6, lane = tid & 63;
    const int q = lane >> 4, r = lane & 15;
    const int strm  = w & 1;
    const int shalf = (w >> 1) & 1;
    const int thalf = w >> 2;
    const int bh = blockIdx.x, qt = blockIdx.y;
    const float lamv = lam[bh & (Hn - 1)];

    bf16_t* sK1 = smem;
    bf16_t* sK2 = smem + 4096;
    bf16_t* sVt = smem + 8192;                    // [d][s], swizzled
    bf16_t* sPw = smem + 12288 + w * 1280;        // [32 t][stride 40]
    float*  out_s = (float*)(smem + 12288);       // 4096 f32, overlays sP
    float*  lsh   = (float*)smem;                 // [8][32] f32, overlays sK1
    float*  sred  = (float*)(smem + 4096);        // 16 f32, overlays sK2

    const size_t HT = (size_t)TKn * DHn;          // 65536
    const bf16_t* qg  = q12 + ((size_t)strm * 64 + bh) * HT
                      + ((size_t)qt * 64 + thalf * 32) * 64;
    const bf16_t* k1g = k12v + (size_t)bh * HT;
    const bf16_t* k2g = k12v + (size_t)(64 + bh) * HT;
    const bf16_t* vg  = k12v + (size_t)(128 + bh) * HT;   // V^T: [d][t]

    // Q fragments in registers (B-operand): t = nj*16 + r, k = ks*32 + q*8
    bf16x8 fQ[2][2];
#pragma unroll
    for (int nj = 0; nj < 2; ++nj)
#pragma unroll
        for (int ks = 0; ks < 2; ++ks)
            fQ[nj][ks] = *(const bf16x8*)(qg + (size_t)(nj * 16 + r) * 64 + ks * 32 + q * 8);

    f32x4 O[2][4];          // [mt (t-subtile)][j (d-subtile)]
    float lpart[2] = {0.f, 0.f};   // [nj], for t = nj*16 + r
#pragma unroll
    for (int i = 0; i < 2; ++i)
#pragma unroll
        for (int j = 0; j < 4; ++j) O[i][j] = (f32x4){0.f, 0.f, 0.f, 0.f};

    // staging: 3 GLDS chunks per thread (K1, K2, V), 16 B each
    const int crow = tid >> 3;                    // 0..63
    const int ccg  = (tid & 7) ^ (crow & 7);      // source-address swizzle
    const bf16_t* sK = strm ? sK2 : sK1;

    for (int st = 0; st < TKn / 64; ++st) {
        __syncthreads();   // prior tile's readers done
        GLDS16(k1g + (size_t)st * 4096 + crow * 64 + ccg * 8, smem + (size_t)tid * 8);
        GLDS16(k2g + (size_t)st * 4096 + crow * 64 + ccg * 8, smem + 4096 + (size_t)tid * 8);
        GLDS16(vg + (size_t)crow * 1024 + st * 64 + ccg * 8,  smem + 8192 + (size_t)tid * 8);
        __syncthreads();   // data visible (barrier drains vmcnt)

        // ---- S^T[s 32][t 32] = K_half · Q^T ----
        f32x4 S[2][2];
#pragma unroll
        for (int mi = 0; mi < 2; ++mi)
#pragma unroll
            for (int nj = 0; nj < 2; ++nj) S[mi][nj] = (f32x4){0.f, 0.f, 0.f, 0.f};
#pragma unroll
        for (int ks = 0; ks < 2; ++ks) {
            bf16x8 fK[2];
#pragma unroll
            for (int mi = 0; mi < 2; ++mi) {
                const int row = shalf * 32 + mi * 16 + r;
                const int g = (ks * 4 + q) ^ (row & 7);
                fK[mi] = *(const bf16x8*)&sK[row * 64 + g * 8];
            }
#pragma unroll
            for (int mi = 0; mi < 2; ++mi)
#pragma unroll
                for (int nj = 0; nj < 2; ++nj)
                    S[mi][nj] = __builtin_amdgcn_mfma_f32_16x16x32_bf16(fK[mi], fQ[nj][ks], S[mi][nj], 0, 0, 0);
        }

        // ---- exp2 + P -> wave-private strip [t][s-local], l accumulate ----
#pragma unroll
        for (int nj = 0; nj < 2; ++nj) {
            float ps = 0.f;
#pragma unroll
            for (int mi = 0; mi < 2; ++mi) {
                bf16x4 pk;
#pragma unroll
                for (int e = 0; e < 4; ++e) {
                    const float p = __builtin_amdgcn_exp2f(S[mi][nj][e] * C_SCALE);
                    ps += p;
                    pk[e] = (bf16_t)p;
                }
                *(bf16x4*)&sPw[(nj * 16 + r) * 40 + mi * 16 + q * 4] = pk;
            }
            lpart[nj] += ps;
        }

        // ---- O[t 32][d 64] += P · V^T (k = 32, single MFMA step) ----
        bf16x8 fV[4], fP[2];
#pragma unroll
        for (int j = 0; j < 4; ++j) {
            const int d = j * 16 + r;
            const int g = (shalf * 4 + q) ^ (d & 7);
            fV[j] = *(const bf16x8*)&sVt[d * 64 + g * 8];
        }
#pragma unroll
        for (int mt = 0; mt < 2; ++mt)
            fP[mt] = *(const bf16x8*)&sPw[(mt * 16 + r) * 40 + q * 8];
#pragma unroll
        for (int mt = 0; mt < 2; ++mt)
#pragma unroll
            for (int j = 0; j < 4; ++j)
                O[mt][j] = __builtin_amdgcn_mfma_f32_16x16x32_bf16(fP[mt], fV[j], O[mt][j], 0, 0, 0);
    }

    // ---- l: reduce across q-lanes -> lane r holds half-sum for t = nj*16+r ----
    lpart[0] += __shfl_xor(lpart[0], 16); lpart[0] += __shfl_xor(lpart[0], 32);
    lpart[1] += __shfl_xor(lpart[1], 16); lpart[1] += __shfl_xor(lpart[1], 32);
    __syncthreads();                 // all waves done with sK/sVt/sP
    if (q == 0) {
        lsh[w * 32 + r] = lpart[0];
        lsh[w * 32 + 16 + r] = lpart[1];
    }
    __syncthreads();

    // scale coefficient per t-row: strm0 -> +1/l, strm1 -> -lam/l (l = both halves)
    float coef[2][4];
#pragma unroll
    for (int mt = 0; mt < 2; ++mt)
#pragma unroll
        for (int e = 0; e < 4; ++e) {
            const int tl = mt * 16 + q * 4 + e;
            const float lf = lsh[w * 32 + tl] + lsh[(w ^ 2) * 32 + tl];
            coef[mt][e] = strm ? (-lamv / lf) : (1.f / lf);
        }

    // ---- merge the 4 (strm,shalf) partials per t-half into out_s ----
#pragma unroll
    for (int k = 0; k < 4; ++k) {
        if ((w & 3) == k) {
#pragma unroll
            for (int mt = 0; mt < 2; ++mt)
#pragma unroll
                for (int j = 0; j < 4; ++j)
#pragma unroll
                    for (int e = 0; e < 4; ++e) {
                        const int row = thalf * 32 + mt * 16 + q * 4 + e;
                        const int idx = row * 64 + j * 16 + r;
                        const float val = O[mt][j][e] * coef[mt][e];
                        if (k == 0) out_s[idx] = val;
                        else        out_s[idx] += val;
                    }
        }
        __syncthreads();
    }

    // ---- readout: coalesced bf16 store + GN partial sums ----
    const int orow = tid >> 3, oc = (tid & 7) * 8;
    f32x4 a = *(const f32x4*)&out_s[orow * 64 + oc];
    f32x4 b = *(const f32x4*)&out_s[orow * 64 + oc + 4];
    bf16x8 ov;
    float ssum = 0.f, ssq = 0.f;
#pragma unroll
    for (int i = 0; i < 4; ++i) {
        ov[i] = (bf16_t)a[i];     ssum += a[i]; ssq += a[i] * a[i];
        ov[4 + i] = (bf16_t)b[i]; ssum += b[i]; ssq += b[i] * b[i];
    }
    *(bf16x8*)&out[((size_t)bh * TQn + (size_t)qt * 64 + orow) * DHn + oc] = ov;

#pragma unroll
    for (int d = 1; d < 64; d <<= 1) {
        ssum += __shfl_xor(ssum, d);
        ssq  += __shfl_xor(ssq, d);
    }
    if (lane == 0) { sred[w] = ssum; sred[8 + w] = ssq; }
    __syncthreads();
    if (tid == 0) {
        float ts = 0.f, tq = 0.f;
#pragma unroll
        for (int i = 0; i < 8; ++i) { ts += sred[i]; tq += sred[8 + i]; }
        atomicAdd(&stats[bh], ts);
        atomicAdd(&stats[64 + bh], tq);
    }
}

// ---------------------------------------------------------------------------
// GroupNorm apply (mu/rstd from atomic sums) + transpose -> y bf16 [B*T,H*DH]
// ---------------------------------------------------------------------------
__global__ __launch_bounds__(256)
void gn_apply(const bf16_t* __restrict__ attn, const float* __restrict__ stats,
              const float* __restrict__ gamma, const float* __restrict__ beta,
              bf16_t* __restrict__ y)
{
    const int f = blockIdx.x * 256 + threadIdx.x;   // 8-elem group, 0..524287
    const int d8 = (f & 7) << 3;
    const int t  = (f >> 3) & 1023;
    const int bh = f >> 13;
    const int h  = bh & 15;
    const int b  = bh >> 4;
    const float s1 = stats[bh], s2 = stats[64 + bh];
    const float mu = s1 * (1.f / 65536.f);
    const float var = s2 * (1.f / 65536.f) - mu * mu;
    const float rstd = rsqrtf(var + EPSv);
    bf16x8 v = *(const bf16x8*)&attn[((size_t)bh << 16) + t * 64 + d8];
    const int c = h * 64 + d8;
    const float* gp = gamma + c;
    const float* bp = beta + c;
    bf16x8 o;
#pragma unroll
    for (int i = 0; i < 8; ++i)
        o[i] = (bf16_t)(((float)v[i] - mu) * rstd * gp[i] + bp[i]);
    *(bf16x8*)&y[((size_t)(b * 1024 + t)) * 1024 + c] = o;
}

// ---------------------------------------------------------------------------
extern "C" void kernel_launch(void* const* d_in, const int* in_sizes, int n_in,
                              void* d_out, int out_size, void* d_ws, size_t ws_size,
                              hipStream_t stream)
{
    const float* x    = (const float*)d_in[0];
    const float* enc  = (const float*)d_in[1];
    const float* Q1w  = (const float*)d_in[2];
    const float* Q1b  = (const float*)d_in[3];
    const float* Q2w  = (const float*)d_in[4];
    const float* Q2b  = (const float*)d_in[5];
    const float* K1w  = (const float*)d_in[6];
    const float* K1b  = (const float*)d_in[7];
    const float* K2w  = (const float*)d_in[8];
    const float* K2b  = (const float*)d_in[9];
    const float* Vw   = (const float*)d_in[10];
    const float* Vb   = (const float*)d_in[11];
    const float* lam  = (const float*)d_in[12];
    const float* gng  = (const float*)d_in[13];
    const float* gnb  = (const float*)d_in[14];
    const float* outw = (const float*)d_in[15];
    const float* outb = (const float*)d_in[16];
    float* out = (float*)d_out;

    // workspace layout (bf16 elems unless noted)
    bf16_t* xb   = (bf16_t*)d_ws;            // 4,194,304
    bf16_t* encb = xb   + 4194304;           // 4,194,304
    bf16_t* wq   = encb + 4194304;           // 2,097,152  [Q1w|Q2w]
    bf16_t* wkv  = wq   + 2097152;           // 3,145,728  [K1w|K2w|Vw]
    bf16_t* wob  = wkv  + 3145728;           // 1,048,576
    bf16_t* q12  = wob  + 1048576;           // 8,388,608  [2][B][H][T][D]
    bf16_t* k12v = q12  + 8388608;           // 12,582,912 [K1|K2: t,d][V: d,t]
    bf16_t* yb   = k12v + 12582912;          // 4,194,304
    bf16_t* attnb= yb   + 4194304;           // 4,194,304
    float*  stats= (float*)(attnb + 4194304);// 128 fp32

    cvt_all<<<7168, 256, 0, stream>>>(x, enc, Q1w, Q2w, K1w, K2w, Vw, outw,
                                      xb, encb, wq, wkv, wob, stats);

    gemm_proj<<<dim3(40, 32), 256, 0, stream>>>(xb, encb, wq, wkv,
                                                Q1b, Q2b, K1b, K2b, Vb,
                                                q12, k12v);

    diff_attn_mfma<<<dim3(64, 16), 512, 0, stream>>>(q12, k12v, lam, attnb, stats);

    gn_apply<<<2048, 256, 0, stream>>>(attnb, stats, gng, gnb, yb);

    gemm_out<<<dim3(8, 32), 256, 0, stream>>>(yb, wob, outb, out);
}